// Round 1
// baseline (842.308 us; speedup 1.0000x reference)
//
#include <hip/hip_runtime.h>
#include <hip/hip_bf16.h>

// Problem constants
#define B_    128
#define G_    10000
#define KW_   20
#define C_    3
#define LAT_  2000
#define GC_   30000      // G*C
#define INLEN_ 200000    // N_LOCI*2

#define KP1_  30016      // h row stride (938*32), cols 30000..30015 zero
#define KP2_  2016       // z row stride (63*32),  cols 2000..2015   zero
#define NCHUNK_ 16       // FC1 split-K chunks

typedef short bf16x8 __attribute__((ext_vector_type(8)));
typedef float f32x4  __attribute__((ext_vector_type(4)));

__device__ __forceinline__ float leaky(float x) { return x >= 0.f ? x : 0.1f * x; }

__device__ __forceinline__ unsigned short f2bf(float f) {
    union { float f; unsigned u; } v; v.f = f;
    unsigned r = v.u + 0x7fffu + ((v.u >> 16) & 1u);   // round-to-nearest-even
    return (unsigned short)(r >> 16);
}
__device__ __forceinline__ float bf2f(unsigned short u) {
    union { unsigned u; float f; } v; v.u = ((unsigned)u) << 16; return v.f;
}

__device__ __forceinline__ bf16x8 pack_bf(float4 a, float4 b) {
    bf16x8 r;
    r[0] = (short)f2bf(a.x); r[1] = (short)f2bf(a.y);
    r[2] = (short)f2bf(a.z); r[3] = (short)f2bf(a.w);
    r[4] = (short)f2bf(b.x); r[5] = (short)f2bf(b.y);
    r[6] = (short)f2bf(b.z); r[7] = (short)f2bf(b.w);
    return r;
}

// ---------------------------------------------------------------------------
// Kernel 1: encoder grouped conv.  h[b, g*3+c] = leaky(sum_k x[b,g*20+k]*w[g,c,k] + b[g,c])
// h stored bf16 with padded row stride KP1_ (pad cols zeroed here).
// ---------------------------------------------------------------------------
__global__ __launch_bounds__(256) void k_enc(const float* __restrict__ x,
                                             const float* __restrict__ w,
                                             const float* __restrict__ bias,
                                             unsigned short* __restrict__ h) {
    __shared__ float xs[5120];                 // 256 groups * 20 floats = 20 KB
    const int t = threadIdx.x;
    const int g0 = blockIdx.x * 256;
    const int b  = blockIdx.y;

    // zero the K-pad of this batch row once
    if (blockIdx.x == 0 && t < (KP1_ - GC_))
        h[(size_t)b * KP1_ + GC_ + t] = 0;

    const float* xrow = x + (size_t)b * INLEN_ + g0 * KW_;
    const int remain = INLEN_ - g0 * KW_;      // >= 320
    float4* xs4 = (float4*)xs;
    #pragma unroll
    for (int j = 0; j < 5; ++j) {
        int idx = j * 256 + t;                 // float4 index
        float4 v = make_float4(0.f, 0.f, 0.f, 0.f);
        if (idx * 4 + 3 < remain) v = ((const float4*)xrow)[idx];
        xs4[idx] = v;
    }
    __syncthreads();

    const int g = g0 + t;
    if (g >= G_) return;

    float wl[60];
    const float4* w4 = (const float4*)(w + (size_t)g * 60);
    #pragma unroll
    for (int i = 0; i < 15; ++i) {
        float4 v = w4[i];
        wl[4*i] = v.x; wl[4*i+1] = v.y; wl[4*i+2] = v.z; wl[4*i+3] = v.w;
    }
    float xr[20];
    const float4* xl4 = (const float4*)(xs + t * KW_);
    #pragma unroll
    for (int i = 0; i < 5; ++i) {
        float4 v = xl4[i];
        xr[4*i] = v.x; xr[4*i+1] = v.y; xr[4*i+2] = v.z; xr[4*i+3] = v.w;
    }
    unsigned short* hp = h + (size_t)b * KP1_ + g * C_;
    #pragma unroll
    for (int c = 0; c < C_; ++c) {
        float s = bias[g * C_ + c];
        #pragma unroll
        for (int k = 0; k < KW_; ++k) s += xr[k] * wl[c * KW_ + k];
        hp[c] = f2bf(leaky(s));
    }
}

// ---------------------------------------------------------------------------
// FC GEMM, barrier-free / LDS-free:  C[m,n] = sum_k A[m,k] * W[n,k]   (M=128)
// One wave owns a 128m x 16n tile over a K-chunk. Fragments loaded directly
// from global per lane (A: bf16x8 = 16B; W: 2x float4 -> bf16 in-register),
// ping-pong register prefetch of the next K-step -> no vmcnt(0) drains, deep MLP.
// A rows padded to KP (zeros beyond K) so no inner K-guards; W tail loads are
// address-clamped (values multiply the zero pad -> harmless).
// MODE 0 (FC1): blockIdx.x = 16 chunks x 32 n-blocks, chunk = blockIdx.x & 15
//               (same-chunk blocks land on one XCD -> A slice stays in its L2);
//               writes fp32 partials outp[chunk][128][N].
// MODE 1 (FC2): single chunk; out = bf16(leaky(C + bias[n])).
// ---------------------------------------------------------------------------
template <int MODE>
__global__ __launch_bounds__(256, 2) void k_fc(const unsigned short* __restrict__ A,
                                               const float* __restrict__ W,
                                               const float* __restrict__ bias,
                                               float* __restrict__ outp,
                                               unsigned short* __restrict__ outb,
                                               int N, int K, int KP) {
    const int t = threadIdx.x;
    const int wave = t >> 6, lane = t & 63, quad = lane >> 4, l16 = lane & 15;

    int chunk, nw, s0, s1;
    if (MODE == 0) {
        chunk = blockIdx.x & (NCHUNK_ - 1);
        nw = (blockIdx.x >> 4) * 4 + wave;         // 0..127, valid < 125
        const int steps = KP >> 5;                 // 938
        s0 = (steps * chunk) >> 4;
        s1 = (steps * (chunk + 1)) >> 4;
    } else {
        chunk = 0;
        nw = blockIdx.x * 4 + wave;                // 0..1875, valid < 1875
        s0 = 0;
        s1 = KP >> 5;                              // 63
    }
    const int NW = (N + 15) >> 4;
    const bool valid = nw < NW;
    const int n0 = (valid ? nw : NW - 1) << 4;
    const int wrow = min(n0 + l16, N - 1);

    const float* Wp = W + (size_t)wrow * K;
    const unsigned short* Ap = A + (size_t)l16 * KP;
    const int kclamp = K - 8;

    f32x4 acc[8];
    #pragma unroll
    for (int i = 0; i < 8; ++i) acc[i] = (f32x4){0.f, 0.f, 0.f, 0.f};

    const int kq0 = (s0 << 5) + (quad << 3);

    // prologue: issue step-s0 loads (W first: longest latency)
    const int kw0 = min(kq0, kclamp);
    float4 w0 = *(const float4*)(Wp + kw0);
    float4 w1 = *(const float4*)(Wp + kw0 + 4);
    bf16x8 a_cur[8];
    #pragma unroll
    for (int mi = 0; mi < 8; ++mi)
        a_cur[mi] = *(const bf16x8*)(Ap + (size_t)mi * 16 * KP + kq0);
    bf16x8 w_cur = pack_bf(w0, w1);

    #pragma unroll 2
    for (int s = s0; s < s1; ++s) {
        const int kn = (s + 1 < s1) ? ((s + 1) << 5) + (quad << 3) : kq0;
        const int kw = min(kn, kclamp);
        // issue next-step loads before consuming current -> 2 K-steps in flight
        float4 nw0 = *(const float4*)(Wp + kw);
        float4 nw1 = *(const float4*)(Wp + kw + 4);
        bf16x8 a_nxt[8];
        #pragma unroll
        for (int mi = 0; mi < 8; ++mi)
            a_nxt[mi] = *(const bf16x8*)(Ap + (size_t)mi * 16 * KP + kn);
        #pragma unroll
        for (int mi = 0; mi < 8; ++mi)
            acc[mi] = __builtin_amdgcn_mfma_f32_16x16x32_bf16(a_cur[mi], w_cur, acc[mi], 0, 0, 0);
        w_cur = pack_bf(nw0, nw1);
        #pragma unroll
        for (int mi = 0; mi < 8; ++mi) a_cur[mi] = a_nxt[mi];
    }

    if (!valid) return;

    if (MODE == 0) {
        float* op = outp + (size_t)chunk * 128 * N + n0 + l16;
        #pragma unroll
        for (int mi = 0; mi < 8; ++mi) {
            const int row = mi * 16 + quad * 4;
            #pragma unroll
            for (int r = 0; r < 4; ++r)
                op[(size_t)(row + r) * N] = acc[mi][r];
        }
    } else {
        const float bv = bias[n0 + l16];
        unsigned short* ob = outb + n0 + l16;
        #pragma unroll
        for (int mi = 0; mi < 8; ++mi) {
            const int row = mi * 16 + quad * 4;
            #pragma unroll
            for (int r = 0; r < 4; ++r)
                ob[(size_t)(row + r) * N] = f2bf(leaky(acc[mi][r] + bv));
        }
    }
}

// ---------------------------------------------------------------------------
// Kernel 3: reduce 16 split-K partials + bias + leaky -> z bf16 [128][KP2_]
// (also zeroes the K-pad cols of z)
// ---------------------------------------------------------------------------
__global__ __launch_bounds__(256) void k_red(const float* __restrict__ zp,
                                             const float* __restrict__ bias,
                                             unsigned short* __restrict__ z) {
    const int n = blockIdx.x * 256 + threadIdx.x;   // grid.x = 8 -> 2048 >= KP2_
    const int b = blockIdx.y;
    if (n >= KP2_) return;
    if (n < LAT_) {
        float s = bias[n];
        #pragma unroll
        for (int c = 0; c < NCHUNK_; ++c)
            s += zp[(size_t)c * 128 * LAT_ + b * LAT_ + n];
        z[(size_t)b * KP2_ + n] = f2bf(leaky(s));
    } else {
        z[(size_t)b * KP2_ + n] = 0;
    }
}

// ---------------------------------------------------------------------------
// Kernel 5: decoder conv-transpose + sigmoid.
// out[b, g*20+k] = sigmoid(dec_b[g] + sum_c d[b,g*3+c]*w[g,c,k])
// ---------------------------------------------------------------------------
__global__ __launch_bounds__(256) void k_dec(const unsigned short* __restrict__ d,
                                             const float* __restrict__ w,
                                             const float* __restrict__ bias,
                                             float* __restrict__ out) {
    const int t = threadIdx.x;
    const int g = blockIdx.x * 256 + t;
    const int b = blockIdx.y;
    if (g >= G_) return;

    const unsigned short* dp = d + (size_t)b * GC_ + g * C_;
    float dv0 = bf2f(dp[0]), dv1 = bf2f(dp[1]), dv2 = bf2f(dp[2]);

    float wl[60];
    const float4* w4 = (const float4*)(w + (size_t)g * 60);
    #pragma unroll
    for (int i = 0; i < 15; ++i) {
        float4 v = w4[i];
        wl[4*i] = v.x; wl[4*i+1] = v.y; wl[4*i+2] = v.z; wl[4*i+3] = v.w;
    }
    const float bg = bias[g];
    float o[20];
    #pragma unroll
    for (int k = 0; k < KW_; ++k) {
        float s = bg + dv0 * wl[k] + dv1 * wl[20 + k] + dv2 * wl[40 + k];
        o[k] = 1.f / (1.f + __expf(-s));
    }
    float4* op = (float4*)(out + (size_t)b * INLEN_ + g * KW_);
    #pragma unroll
    for (int i = 0; i < 5; ++i)
        op[i] = make_float4(o[4*i], o[4*i+1], o[4*i+2], o[4*i+3]);
}

// ---------------------------------------------------------------------------
extern "C" void kernel_launch(void* const* d_in, const int* in_sizes, int n_in,
                              void* d_out, int out_size, void* d_ws, size_t ws_size,
                              hipStream_t stream) {
    const float* x        = (const float*)d_in[0];
    const float* enc_w    = (const float*)d_in[1];
    const float* enc_b    = (const float*)d_in[2];
    const float* enc_fc_w = (const float*)d_in[3];
    const float* enc_fc_b = (const float*)d_in[4];
    const float* dec_fc_w = (const float*)d_in[5];
    const float* dec_fc_b = (const float*)d_in[6];
    const float* dec_w    = (const float*)d_in[7];
    const float* dec_b    = (const float*)d_in[8];
    float* out = (float*)d_out;

    // workspace layout (~32.3 MB total, 16B-aligned offsets)
    char* ws = (char*)d_ws;
    unsigned short* h  = (unsigned short*)ws;               //  7,684,096 B : h bf16 [128][30016]
    float*          zp = (float*)(ws + 7684096);            // 16,384,000 B : z partials [16][128][2000]
    unsigned short* z  = (unsigned short*)(ws + 24068096);  //    516,096 B : z bf16 [128][2016]
    unsigned short* dd = (unsigned short*)(ws + 24584192);  //  7,680,000 B : d bf16 [128][30000]

    k_enc<<<dim3(40, 128), 256, 0, stream>>>(x, enc_w, enc_b, h);
    // FC1: N=2000, K=30000 (padded 30016 = 938 steps), 16 K-chunks x 32 n-blocks
    k_fc<0><<<dim3(NCHUNK_ * 32), 256, 0, stream>>>(h, enc_fc_w, nullptr, zp, nullptr, LAT_, GC_, KP1_);
    k_red<<<dim3(8, 128), 256, 0, stream>>>(zp, enc_fc_b, z);
    // FC2: N=30000 (1875 n-waves -> 469 blocks), K=2000 (padded 2016 = 63 steps)
    k_fc<1><<<dim3(469), 256, 0, stream>>>(z, dec_fc_w, dec_fc_b, nullptr, dd, GC_, LAT_, KP2_);
    k_dec<<<dim3(40, 128), 256, 0, stream>>>(dd, dec_w, dec_b, out);
}